// Round 11
// baseline (118.766 us; speedup 1.0000x reference)
//
#include <hip/hip_runtime.h>
#include <hip/hip_bf16.h>
#include <math.h>

#define NN 50000
#define NE 800000
#define HD 128
#define NB ((NN + 63) >> 6)                         // 782 buckets (64 nodes each)
#define GCAP 1536                                   // max edges/bucket (mean ~1024, +16 sigma)
#define PART_EPB 2048
#define PART_NBLK ((NE + PART_EPB - 1) / PART_EPB)  // 391
#define NBG ((NN + 63) / 64)                        // 782 gemm blocks

typedef unsigned int u32;
typedef unsigned short u16;
typedef __attribute__((ext_vector_type(8))) __bf16 bf16x8;
typedef __attribute__((ext_vector_type(4))) float f32x4;

__device__ __forceinline__ u16 f2bf(float f) {
    u32 u = __float_as_uint(f);
    u32 r = u + 0x7FFFu + ((u >> 16) & 1u);   // round-to-nearest-even
    return (u16)(r >> 16);
}
__device__ __forceinline__ void unpack8(uint4 p, float* f) {
    f[0] = __uint_as_float(p.x << 16); f[1] = __uint_as_float(p.x & 0xFFFF0000u);
    f[2] = __uint_as_float(p.y << 16); f[3] = __uint_as_float(p.y & 0xFFFF0000u);
    f[4] = __uint_as_float(p.z << 16); f[5] = __uint_as_float(p.z & 0xFFFF0000u);
    f[6] = __uint_as_float(p.w << 16); f[7] = __uint_as_float(p.w & 0xFFFF0000u);
}

// ---- partition edges into 64-node buckets; blocks >= PART_NBLK convert W ----
__global__ __launch_bounds__(256) void part_kernel(
        const int* __restrict__ src, const int* __restrict__ dst,
        const float* __restrict__ W,
        u32* __restrict__ bcnt, u32* __restrict__ ebuf, u16* __restrict__ wf) {
    __shared__ u32 lh[NB];
    __shared__ u32 lbase[NB];
    const int tid = threadIdx.x;
    if (blockIdx.x >= PART_NBLK) {
        // W -> MFMA fragment layout. Tile t=c0*4+k0; lane ln elem j holds
        // W[k0*32+(ln>>4)*8+j][(ln&15)*8+c0] (8 consecutive out-cols per lane).
        int idx = (blockIdx.x - PART_NBLK) * 256 + tid;   // exactly HD*HD threads
        int t  = idx >> 9;
        int c0 = t >> 2, k0 = t & 3;
        int ln = (idx >> 3) & 63;
        int j  = idx & 7;
        int k  = k0 * 32 + (ln >> 4) * 8 + j;
        int c  = (ln & 15) * 8 + c0;
        wf[idx] = f2bf(W[k * HD + c]);
        return;
    }
    const int e0 = blockIdx.x * PART_EPB;
    for (int i = tid; i < NB; i += 256) lh[i] = 0u;
    __syncthreads();
    #pragma unroll
    for (int j = 0; j < PART_EPB / 256; ++j) {
        int e = e0 + j * 256 + tid;
        if (e < NE) atomicAdd(&lh[dst[e] >> 6], 1u);
    }
    __syncthreads();
    for (int i = tid; i < NB; i += 256) {
        u32 c = lh[i];
        lbase[i] = c ? atomicAdd(&bcnt[i], c) : 0u;
        lh[i] = 0u;                       // reuse as local cursor
    }
    __syncthreads();
    #pragma unroll
    for (int j = 0; j < PART_EPB / 256; ++j) {
        int e = e0 + j * 256 + tid;
        if (e < NE) {
            int d = dst[e], s = src[e];
            int bkt = d >> 6;
            u32 r = atomicAdd(&lh[bkt], 1u);
            u32 pos = lbase[bkt] + r;
            if (pos < GCAP)
                ebuf[(size_t)bkt * GCAP + pos] = (u32)s | ((u32)(d & 63) << 16);
        }
    }
}

// ---- per-bucket CSR build in LDS (base computed in-block) + dinv ----
__global__ __launch_bounds__(256) void bucket_kernel(const u32* __restrict__ ebuf,
                                                     const u32* __restrict__ bcnt,
                                                     u32* __restrict__ rowptr,
                                                     float* __restrict__ dinv,
                                                     u16* __restrict__ srclist) {
    __shared__ u32 cnt[64], loc[64], cur[64];
    __shared__ u16 stage[GCAP];
    __shared__ u32 wred[4];
    const int tid = threadIdx.x;
    const int lane = tid & 63, wv = tid >> 6;
    const int b = blockIdx.x;
    const int n0 = b << 6;

    // base = sum of bcnt[0..b)
    u32 partial = 0;
    for (int i = tid; i < b; i += 256) partial += bcnt[i];
    #pragma unroll
    for (int off = 1; off < 64; off <<= 1) partial += __shfl_xor(partial, off, 64);
    if (lane == 0) wred[wv] = partial;
    if (tid < 64) { cnt[tid] = 0u; cur[tid] = 0u; }
    __syncthreads();
    const u32 base = wred[0] + wred[1] + wred[2] + wred[3];

    u32 m = bcnt[b]; if (m > GCAP) m = GCAP;
    for (u32 i = tid; i < m; i += 256)
        atomicAdd(&cnt[ebuf[(size_t)b * GCAP + i] >> 16], 1u);
    __syncthreads();
    if (tid < 64) {                       // exclusive scan of 64 counts, one wave
        u32 c = cnt[tid];
        u32 inc = c;
        #pragma unroll
        for (int off = 1; off < 64; off <<= 1) {
            u32 y = __shfl_up(inc, off, 64);
            if (tid >= off) inc += y;
        }
        loc[tid] = inc - c;
        int node = n0 + tid;
        if (node < NN) {
            rowptr[node] = base + inc - c;
            dinv[node] = rsqrtf((float)(c + 1u));   // +1 self loop
        }
    }
    __syncthreads();
    for (u32 i = tid; i < m; i += 256) {
        u32 v = ebuf[(size_t)b * GCAP + i];
        u32 nl = v >> 16;
        u32 r = atomicAdd(&cur[nl], 1u);
        stage[loc[nl] + r] = (u16)(v & 0xFFFFu);
    }
    __syncthreads();
    for (u32 i = tid; i < m; i += 256) srclist[base + i] = stage[i];
    if (b == 0 && tid == 0) rowptr[NN] = NE;
}

// ---- xscale: xs[u] = bf16(dinv[u] * x[u])  (wide streaming pass) ----
__global__ __launch_bounds__(256) void xscale_kernel(const float* __restrict__ x,
                                                     const float* __restrict__ dinv,
                                                     u16* __restrict__ xs) {
    int idx = blockIdx.x * blockDim.x + threadIdx.x;   // NN*HD/4 threads
    float dv = dinv[idx >> 5];
    const float4 v = reinterpret_cast<const float4*>(x)[idx];
    u32 lo = (u32)f2bf(dv * v.x) | ((u32)f2bf(dv * v.y) << 16);
    u32 hi = (u32)f2bf(dv * v.z) | ((u32)f2bf(dv * v.w) << 16);
    reinterpret_cast<uint2*>(xs)[idx] = make_uint2(lo, hi);
}

// ---- aggregation: 1 wave/node; 4 edge slots x 16 feature-lanes; plain loop
// (TLP-saturated gather -- no manual unroll, per R5 vs R7/R10 evidence) ----
__global__ __launch_bounds__(256) void agg_kernel(
        const u16* __restrict__ xs, const u32* __restrict__ rowptr,
        const u16* __restrict__ srclist, const float* __restrict__ dinv,
        u16* __restrict__ aggX) {
    int v = (blockIdx.x * blockDim.x + threadIdx.x) >> 6;
    if (v >= NN) return;
    const int lane = threadIdx.x & 63;
    const int eq = lane >> 4;      // edge slot 0..3
    const int fl = lane & 15;      // 16B feature slice
    float acc[8] = {};
    if (eq == 0) {                 // self loop (xs already carries dinv[v])
        uint4 sv = reinterpret_cast<const uint4*>(xs + (size_t)v * HD)[fl];
        float f[8]; unpack8(sv, f);
        #pragma unroll
        for (int j = 0; j < 8; ++j) acc[j] = f[j];
    }
    const u32 rs = rowptr[v], re = rowptr[v + 1];
    for (u32 i = rs + eq; i < re; i += 4) {
        u32 u = (u32)srclist[i];
        uint4 mu = reinterpret_cast<const uint4*>(xs + (size_t)u * HD)[fl];
        float f[8]; unpack8(mu, f);
        #pragma unroll
        for (int j = 0; j < 8; ++j) acc[j] += f[j];
    }
    #pragma unroll
    for (int j = 0; j < 8; ++j) {
        acc[j] += __shfl_xor(acc[j], 16, 64);
        acc[j] += __shfl_xor(acc[j], 32, 64);
    }
    if (eq == 0) {
        const float dv = dinv[v];
        u32 w[4];
        #pragma unroll
        for (int q = 0; q < 4; ++q)
            w[q] = (u32)f2bf(dv * acc[2 * q]) | ((u32)f2bf(dv * acc[2 * q + 1]) << 16);
        reinterpret_cast<uint4*>(aggX + (size_t)v * HD)[fl] =
            make_uint4(w[0], w[1], w[2], w[3]);
    }
}

// ---- MFMA GEMM: agg = aggX @ W + b; coalesced uint4 C-stores; BN partials ----
__global__ __launch_bounds__(256) void gemm_kernel(
        const u16* __restrict__ aggX, const u16* __restrict__ wf,
        const float* __restrict__ bias,
        u16* __restrict__ agg, float* __restrict__ colpart) {
    __shared__ float cs_l[128];
    __shared__ float cq_l[128];
    const int tid = threadIdx.x;
    if (tid < 128) { cs_l[tid] = 0.f; cq_l[tid] = 0.f; }
    __syncthreads();

    const int lane = tid & 63, wave = tid >> 6;
    const int r0 = blockIdx.x * 64 + wave * 16;
    const int l15 = lane & 15, rgrp = lane >> 4;
    const int rrow = r0 + l15;

    bf16x8 a[4];
    #pragma unroll
    for (int k0 = 0; k0 < 4; ++k0) {
        if (rrow < NN)
            a[k0] = *reinterpret_cast<const bf16x8*>(aggX + (size_t)rrow * HD + k0 * 32 + rgrp * 8);
        else
            a[k0] = bf16x8{};
    }

    f32x4 acc[8];
    #pragma unroll
    for (int c0 = 0; c0 < 8; ++c0) acc[c0] = f32x4{0.f, 0.f, 0.f, 0.f};
    #pragma unroll
    for (int c0 = 0; c0 < 8; ++c0) {
        #pragma unroll
        for (int k0 = 0; k0 < 4; ++k0) {
            bf16x8 b = *reinterpret_cast<const bf16x8*>(wf + ((c0 * 4 + k0) * 64 + lane) * 8);
            acc[c0] = __builtin_amdgcn_mfma_f32_16x16x32_bf16(a[k0], b, acc[c0], 0, 0, 0);
        }
    }

    float4 b4a = *reinterpret_cast<const float4*>(bias + l15 * 8);
    float4 b4b = *reinterpret_cast<const float4*>(bias + l15 * 8 + 4);
    const float bcol[8] = {b4a.x, b4a.y, b4a.z, b4a.w, b4b.x, b4b.y, b4b.z, b4b.w};

    float cp[8] = {}, cq[8] = {};
    #pragma unroll
    for (int reg = 0; reg < 4; ++reg) {
        int row = r0 + rgrp * 4 + reg;
        float v[8];
        #pragma unroll
        for (int c0 = 0; c0 < 8; ++c0) v[c0] = acc[c0][reg] + bcol[c0];
        if (row < NN) {
            u32 w4[4];
            #pragma unroll
            for (int q = 0; q < 4; ++q)
                w4[q] = (u32)f2bf(v[2 * q]) | ((u32)f2bf(v[2 * q + 1]) << 16);
            *reinterpret_cast<uint4*>(agg + (size_t)row * HD + l15 * 8) =
                make_uint4(w4[0], w4[1], w4[2], w4[3]);
            #pragma unroll
            for (int c0 = 0; c0 < 8; ++c0) { cp[c0] += v[c0]; cq[c0] += v[c0] * v[c0]; }
        }
    }
    #pragma unroll
    for (int c0 = 0; c0 < 8; ++c0) {
        cp[c0] += __shfl_xor(cp[c0], 16, 64); cp[c0] += __shfl_xor(cp[c0], 32, 64);
        cq[c0] += __shfl_xor(cq[c0], 16, 64); cq[c0] += __shfl_xor(cq[c0], 32, 64);
    }
    if (rgrp == 0) {
        #pragma unroll
        for (int c0 = 0; c0 < 8; ++c0) {
            atomicAdd(&cs_l[l15 * 8 + c0], cp[c0]);
            atomicAdd(&cq_l[l15 * 8 + c0], cq[c0]);
        }
    }
    __syncthreads();
    if (tid < 128) {
        colpart[(size_t)blockIdx.x * 256 + tid] = cs_l[tid];
        colpart[(size_t)blockIdx.x * 256 + 128 + tid] = cq_l[tid];
    }
}

// ---- fused stats reduce: 64 blocks; last block finalizes sc/sh ----
__global__ __launch_bounds__(256) void redstat_kernel(const float* __restrict__ colpart,
                                                      float* __restrict__ colpart2,
                                                      u32* __restrict__ done,
                                                      const float* __restrict__ gamma,
                                                      const float* __restrict__ beta,
                                                      float* __restrict__ sc,
                                                      float* __restrict__ sh) {
    __shared__ u32 amlast;
    const int slot = threadIdx.x;
    float s = 0.f;
    for (int b = blockIdx.x; b < NBG; b += 64) s += colpart[(size_t)b * 256 + slot];
    colpart2[(size_t)blockIdx.x * 256 + slot] = s;
    __threadfence();
    if (slot == 0) amlast = (atomicAdd(done, 1u) == 63u) ? 1u : 0u;
    __syncthreads();
    if (amlast && slot < 128) {
        float s1 = 0.f, s2 = 0.f;
        for (int b = 0; b < 64; ++b) {
            s1 += colpart2[(size_t)b * 256 + slot];
            s2 += colpart2[(size_t)b * 256 + 128 + slot];
        }
        float m = s1 * (1.f / NN);
        float var = s2 * (1.f / NN) - m * m;
        float inv = rsqrtf(var + 1e-5f);
        float scl = gamma[slot] * inv;
        sc[slot] = scl;
        sh[slot] = beta[slot] - m * scl;
    }
}

// ---- normalize + ReLU + residual ----
__global__ void final_kernel(const u16* __restrict__ agg, const float* __restrict__ last_x,
                             const float* __restrict__ sc, const float* __restrict__ sh,
                             float* __restrict__ out) {
    int idx = blockIdx.x * blockDim.x + threadIdx.x;   // NN*HD/4 threads
    int c0 = (idx * 4) & 127;
    uint2 a = reinterpret_cast<const uint2*>(agg)[idx];
    float4 lx = reinterpret_cast<const float4*>(last_x)[idx];
    float f0 = __uint_as_float(a.x << 16), f1 = __uint_as_float(a.x & 0xFFFF0000u);
    float f2 = __uint_as_float(a.y << 16), f3 = __uint_as_float(a.y & 0xFFFF0000u);
    float4 o;
    o.x = fmaxf(fmaf(f0, sc[c0 + 0], sh[c0 + 0]), 0.f) + lx.x;
    o.y = fmaxf(fmaf(f1, sc[c0 + 1], sh[c0 + 1]), 0.f) + lx.y;
    o.z = fmaxf(fmaf(f2, sc[c0 + 2], sh[c0 + 2]), 0.f) + lx.z;
    o.w = fmaxf(fmaf(f3, sc[c0 + 3], sh[c0 + 3]), 0.f) + lx.w;
    reinterpret_cast<float4*>(out)[idx] = o;
}

extern "C" void kernel_launch(void* const* d_in, const int* in_sizes, int n_in,
                              void* d_out, int out_size, void* d_ws, size_t ws_size,
                              hipStream_t stream) {
    const float* x      = (const float*)d_in[0];
    const float* last_x = (const float*)d_in[1];
    const int*   edge   = (const int*)d_in[2];   // [2][NE]
    const float* W      = (const float*)d_in[3];
    const float* bias   = (const float*)d_in[4];
    const float* gamma  = (const float*)d_in[5];
    const float* beta   = (const float*)d_in[6];
    float* out = (float*)d_out;

    char* ws = (char*)d_ws;
    size_t p = 0;
    auto take = [&](size_t bytes) { size_t r = p; p += (bytes + 255) & ~255ULL; return r; };
    u32*   bcnt     = (u32*)(ws + take((size_t)(NB + 1) * 4));
    u32*   done     = bcnt + NB;
    u32*   ebuf     = (u32*)(ws + take((size_t)NB * GCAP * 4));
    u32*   rowptr   = (u32*)(ws + take((size_t)(NN + 1) * 4));
    u16*   srclist  = (u16*)(ws + take((size_t)NE * 2));
    float* dinv     = (float*)(ws + take((size_t)NN * 4));
    u16*   xs       = (u16*)(ws + take((size_t)NN * HD * 2));
    u16*   aggX     = (u16*)(ws + take((size_t)NN * HD * 2));
    u16*   aggb     = (u16*)(ws + take((size_t)NN * HD * 2));
    u16*   wf       = (u16*)(ws + take((size_t)HD * HD * 2));
    float* colpart  = (float*)(ws + take((size_t)NBG * 256 * 4));
    float* colpart2 = (float*)(ws + take((size_t)64 * 256 * 4));
    float* sc       = (float*)(ws + take((size_t)HD * 4));
    float* sh       = (float*)(ws + take((size_t)HD * 4));

    const int* srcp = edge;
    const int* dstp = edge + NE;

    hipMemsetAsync(bcnt, 0, (size_t)(NB + 1) * 4, stream);
    part_kernel<<<PART_NBLK + 64, 256, 0, stream>>>(srcp, dstp, W, bcnt, ebuf, wf);
    bucket_kernel<<<NB, 256, 0, stream>>>(ebuf, bcnt, rowptr, dinv, srclist);
    xscale_kernel<<<(NN * HD / 4) / 256, 256, 0, stream>>>(x, dinv, xs);
    agg_kernel<<<(NN + 3) / 4, 256, 0, stream>>>(xs, rowptr, srclist, dinv, aggX);
    gemm_kernel<<<NBG, 256, 0, stream>>>(aggX, wf, bias, aggb, colpart);
    redstat_kernel<<<64, 256, 0, stream>>>(colpart, colpart2, done, gamma, beta, sc, sh);
    final_kernel<<<(NN * HD / 4) / 256, 256, 0, stream>>>(aggb, last_x, sc, sh, out);
}

// Round 12
// 111.130 us; speedup vs baseline: 1.0687x; 1.0687x over previous
//
#include <hip/hip_runtime.h>
#include <hip/hip_bf16.h>
#include <math.h>

#define NN 50000
#define NE 800000
#define HD 128
#define NB ((NN + 127) >> 7)                        // 391 buckets (128 nodes each)
#define GCAP 3072                                   // max edges/bucket (mean ~2048)
#define PART_EPB 4096
#define PART_NBLK ((NE + PART_EPB - 1) / PART_EPB)  // 196
#define CONV_NBLK ((NN * HD / 4) / 256)             // 6250
#define NBG ((NN + 63) / 64)                        // 782 gemm blocks

typedef unsigned int u32;
typedef unsigned short u16;
typedef __attribute__((ext_vector_type(8))) __bf16 bf16x8;
typedef __attribute__((ext_vector_type(4))) float f32x4;

__device__ __forceinline__ u16 f2bf(float f) {
    u32 u = __float_as_uint(f);
    u32 r = u + 0x7FFFu + ((u >> 16) & 1u);   // round-to-nearest-even
    return (u16)(r >> 16);
}
__device__ __forceinline__ void unpack8(uint4 p, float* f) {
    f[0] = __uint_as_float(p.x << 16); f[1] = __uint_as_float(p.x & 0xFFFF0000u);
    f[2] = __uint_as_float(p.y << 16); f[3] = __uint_as_float(p.y & 0xFFFF0000u);
    f[4] = __uint_as_float(p.z << 16); f[5] = __uint_as_float(p.z & 0xFFFF0000u);
    f[6] = __uint_as_float(p.w << 16); f[7] = __uint_as_float(p.w & 0xFFFF0000u);
}

// ---- fused prep + partition: blocks [0,PART_NBLK) radix-partition edges;
// blocks [PART_NBLK,..) convert x -> bf16 xh and W -> MFMA fragment wf ----
__global__ __launch_bounds__(256) void prep_part_kernel(
        const int* __restrict__ src, const int* __restrict__ dst,
        const float* __restrict__ x, const float* __restrict__ W,
        u32* __restrict__ bcnt, u32* __restrict__ ebuf,
        u16* __restrict__ xh, u16* __restrict__ wf) {
    __shared__ u32 lh[NB];
    __shared__ u32 lbase[NB];
    const int tid = threadIdx.x;
    if (blockIdx.x >= PART_NBLK) {
        // ---- conversion role ----
        int idx = (blockIdx.x - PART_NBLK) * 256 + tid;   // exactly NN*HD/4
        const float4 v = reinterpret_cast<const float4*>(x)[idx];
        u32 lo = (u32)f2bf(v.x) | ((u32)f2bf(v.y) << 16);
        u32 hi = (u32)f2bf(v.z) | ((u32)f2bf(v.w) << 16);
        reinterpret_cast<uint2*>(xh)[idx] = make_uint2(lo, hi);
        if (idx < HD * HD) {
            // Wf tile t=c0*4+k0; lane ln elem j = W[k0*32+(ln>>4)*8+j][(ln&15)*8+c0]
            int t  = idx >> 9;
            int c0 = t >> 2, k0 = t & 3;
            int ln = (idx >> 3) & 63;
            int j  = idx & 7;
            int k  = k0 * 32 + (ln >> 4) * 8 + j;
            int c  = (ln & 15) * 8 + c0;
            wf[idx] = f2bf(W[k * HD + c]);
        }
        return;
    }
    // ---- partition role ----
    const int e0 = blockIdx.x * PART_EPB;
    for (int i = tid; i < NB; i += 256) lh[i] = 0u;
    __syncthreads();
    #pragma unroll
    for (int j = 0; j < PART_EPB / 256; ++j) {
        int e = e0 + j * 256 + tid;
        if (e < NE) atomicAdd(&lh[dst[e] >> 7], 1u);
    }
    __syncthreads();
    for (int i = tid; i < NB; i += 256) {
        u32 c = lh[i];
        lbase[i] = c ? atomicAdd(&bcnt[i], c) : 0u;
        lh[i] = 0u;                       // reuse as local cursor
    }
    __syncthreads();
    #pragma unroll
    for (int j = 0; j < PART_EPB / 256; ++j) {
        int e = e0 + j * 256 + tid;
        if (e < NE) {
            int d = dst[e], s = src[e];
            int bkt = d >> 7;
            u32 r = atomicAdd(&lh[bkt], 1u);
            u32 pos = lbase[bkt] + r;
            if (pos < GCAP)
                ebuf[(size_t)bkt * GCAP + pos] = (u32)s | ((u32)(d & 127) << 16);
        }
    }
}

// ---- per-bucket CSR build in LDS; base = sum bcnt[0..b) in-block ----
__global__ __launch_bounds__(256) void bucket_kernel(const u32* __restrict__ ebuf,
                                                     const u32* __restrict__ bcnt,
                                                     u32* __restrict__ rowptr,
                                                     float* __restrict__ dinv,
                                                     u16* __restrict__ srclist) {
    __shared__ u32 cnt[128], loc[128], cur[128];
    __shared__ u16 stage[GCAP];
    __shared__ u32 wred[4];
    const int tid = threadIdx.x;
    const int lane = tid & 63, wv = tid >> 6;
    const int b = blockIdx.x;
    const int n0 = b << 7;

    u32 partial = 0;
    for (int i = tid; i < b; i += 256) partial += bcnt[i];
    #pragma unroll
    for (int off = 1; off < 64; off <<= 1) partial += __shfl_xor(partial, off, 64);
    if (lane == 0) wred[wv] = partial;
    if (tid < 128) { cnt[tid] = 0u; cur[tid] = 0u; }
    __syncthreads();
    const u32 base = wred[0] + wred[1] + wred[2] + wred[3];

    u32 m = bcnt[b]; if (m > GCAP) m = GCAP;
    for (u32 i = tid; i < m; i += 256)
        atomicAdd(&cnt[ebuf[(size_t)b * GCAP + i] >> 16], 1u);
    __syncthreads();
    if (tid < 64) {                       // exclusive scan of 128 counts, one wave
        u32 c0 = cnt[2 * tid], c1 = cnt[2 * tid + 1];
        u32 s = c0 + c1, inc = s;
        #pragma unroll
        for (int off = 1; off < 64; off <<= 1) {
            u32 y = __shfl_up(inc, off, 64);
            if (tid >= off) inc += y;
        }
        loc[2 * tid]     = inc - s;
        loc[2 * tid + 1] = inc - s + c0;
    }
    __syncthreads();
    if (tid < 128) {
        int node = n0 + tid;
        if (node < NN) {
            rowptr[node] = base + loc[tid];
            dinv[node] = rsqrtf((float)(cnt[tid] + 1u));   // +1 self loop
        }
    }
    __syncthreads();
    for (u32 i = tid; i < m; i += 256) {
        u32 v = ebuf[(size_t)b * GCAP + i];
        u32 nl = v >> 16;
        u32 r = atomicAdd(&cur[nl], 1u);
        stage[loc[nl] + r] = (u16)(v & 0xFFFFu);
    }
    __syncthreads();
    for (u32 i = tid; i < m; i += 256) srclist[base + i] = stage[i];
    if (b == 0 && tid == 0) rowptr[NN] = NE;
}

// ---- aggregation (R5-exact): 1 wave/node; 4 edge slots x 16 feature-lanes;
// plain loop; per-edge dinv[u] broadcast load ----
__global__ __launch_bounds__(256) void agg_kernel(
        const u16* __restrict__ xh, const u32* __restrict__ rowptr,
        const u16* __restrict__ srclist, const float* __restrict__ dinv,
        u16* __restrict__ aggX) {
    int wid = (blockIdx.x * blockDim.x + threadIdx.x) >> 6;
    if (wid >= NN) return;
    const int lane = threadIdx.x & 63;
    const int eq = lane >> 4;      // edge slot 0..3
    const int fl = lane & 15;      // 16B feature slice
    const int v = wid;
    float acc[8];
    {
        uint4 sv = reinterpret_cast<const uint4*>(xh + (size_t)v * HD)[fl];
        float f[8]; unpack8(sv, f);
        float s = (eq == 0) ? dinv[v] : 0.f;   // self loop (dv applied again at end)
        #pragma unroll
        for (int j = 0; j < 8; ++j) acc[j] = s * f[j];
    }
    const u32 rs = rowptr[v], re = rowptr[v + 1];
    for (u32 i = rs + eq; i < re; i += 4) {
        u32 u = (u32)srclist[i];
        float du = dinv[u];
        uint4 mu = reinterpret_cast<const uint4*>(xh + (size_t)u * HD)[fl];
        float f[8]; unpack8(mu, f);
        #pragma unroll
        for (int j = 0; j < 8; ++j) acc[j] = fmaf(du, f[j], acc[j]);
    }
    #pragma unroll
    for (int j = 0; j < 8; ++j) {
        acc[j] += __shfl_xor(acc[j], 16, 64);
        acc[j] += __shfl_xor(acc[j], 32, 64);
    }
    if (eq == 0) {
        const float dv = dinv[v];
        u32 w[4];
        #pragma unroll
        for (int q = 0; q < 4; ++q)
            w[q] = (u32)f2bf(dv * acc[2 * q]) | ((u32)f2bf(dv * acc[2 * q + 1]) << 16);
        reinterpret_cast<uint4*>(aggX + (size_t)v * HD)[fl] =
            make_uint4(w[0], w[1], w[2], w[3]);
    }
}

// ---- MFMA GEMM: agg = aggX @ W + b; coalesced uint4 C-stores; BN partials ----
__global__ __launch_bounds__(256) void gemm_kernel(
        const u16* __restrict__ aggX, const u16* __restrict__ wf,
        const float* __restrict__ bias,
        u16* __restrict__ agg, float* __restrict__ colpart) {
    __shared__ float cs_l[128];
    __shared__ float cq_l[128];
    const int tid = threadIdx.x;
    if (tid < 128) { cs_l[tid] = 0.f; cq_l[tid] = 0.f; }
    __syncthreads();

    const int lane = tid & 63, wave = tid >> 6;
    const int r0 = blockIdx.x * 64 + wave * 16;
    const int l15 = lane & 15, rgrp = lane >> 4;
    const int rrow = r0 + l15;

    bf16x8 a[4];
    #pragma unroll
    for (int k0 = 0; k0 < 4; ++k0) {
        if (rrow < NN)
            a[k0] = *reinterpret_cast<const bf16x8*>(aggX + (size_t)rrow * HD + k0 * 32 + rgrp * 8);
        else
            a[k0] = bf16x8{};
    }

    f32x4 acc[8];
    #pragma unroll
    for (int c0 = 0; c0 < 8; ++c0) acc[c0] = f32x4{0.f, 0.f, 0.f, 0.f};
    #pragma unroll
    for (int c0 = 0; c0 < 8; ++c0) {
        #pragma unroll
        for (int k0 = 0; k0 < 4; ++k0) {
            bf16x8 b = *reinterpret_cast<const bf16x8*>(wf + ((c0 * 4 + k0) * 64 + lane) * 8);
            acc[c0] = __builtin_amdgcn_mfma_f32_16x16x32_bf16(a[k0], b, acc[c0], 0, 0, 0);
        }
    }

    float4 b4a = *reinterpret_cast<const float4*>(bias + l15 * 8);
    float4 b4b = *reinterpret_cast<const float4*>(bias + l15 * 8 + 4);
    const float bcol[8] = {b4a.x, b4a.y, b4a.z, b4a.w, b4b.x, b4b.y, b4b.z, b4b.w};

    float cp[8] = {}, cq[8] = {};
    #pragma unroll
    for (int reg = 0; reg < 4; ++reg) {
        int row = r0 + rgrp * 4 + reg;
        float v[8];
        #pragma unroll
        for (int c0 = 0; c0 < 8; ++c0) v[c0] = acc[c0][reg] + bcol[c0];
        if (row < NN) {
            u32 w4[4];
            #pragma unroll
            for (int q = 0; q < 4; ++q)
                w4[q] = (u32)f2bf(v[2 * q]) | ((u32)f2bf(v[2 * q + 1]) << 16);
            *reinterpret_cast<uint4*>(agg + (size_t)row * HD + l15 * 8) =
                make_uint4(w4[0], w4[1], w4[2], w4[3]);
            #pragma unroll
            for (int c0 = 0; c0 < 8; ++c0) { cp[c0] += v[c0]; cq[c0] += v[c0] * v[c0]; }
        }
    }
    #pragma unroll
    for (int c0 = 0; c0 < 8; ++c0) {
        cp[c0] += __shfl_xor(cp[c0], 16, 64); cp[c0] += __shfl_xor(cp[c0], 32, 64);
        cq[c0] += __shfl_xor(cq[c0], 16, 64); cq[c0] += __shfl_xor(cq[c0], 32, 64);
    }
    if (rgrp == 0) {
        #pragma unroll
        for (int c0 = 0; c0 < 8; ++c0) {
            atomicAdd(&cs_l[l15 * 8 + c0], cp[c0]);
            atomicAdd(&cq_l[l15 * 8 + c0], cq[c0]);
        }
    }
    __syncthreads();
    if (tid < 128) {
        colpart[(size_t)blockIdx.x * 256 + tid] = cs_l[tid];
        colpart[(size_t)blockIdx.x * 256 + 128 + tid] = cq_l[tid];
    }
}

// ---- fused stats reduce: 64 blocks; last block finalizes sc/sh ----
__global__ __launch_bounds__(256) void redstat_kernel(const float* __restrict__ colpart,
                                                      float* __restrict__ colpart2,
                                                      u32* __restrict__ done,
                                                      const float* __restrict__ gamma,
                                                      const float* __restrict__ beta,
                                                      float* __restrict__ sc,
                                                      float* __restrict__ sh) {
    __shared__ u32 amlast;
    const int slot = threadIdx.x;
    float s = 0.f;
    for (int b = blockIdx.x; b < NBG; b += 64) s += colpart[(size_t)b * 256 + slot];
    colpart2[(size_t)blockIdx.x * 256 + slot] = s;
    __threadfence();
    if (slot == 0) amlast = (atomicAdd(done, 1u) == 63u) ? 1u : 0u;
    __syncthreads();
    if (amlast && slot < 128) {
        float s1 = 0.f, s2 = 0.f;
        for (int b = 0; b < 64; ++b) {
            s1 += colpart2[(size_t)b * 256 + slot];
            s2 += colpart2[(size_t)b * 256 + 128 + slot];
        }
        float m = s1 * (1.f / NN);
        float var = s2 * (1.f / NN) - m * m;
        float inv = rsqrtf(var + 1e-5f);
        float scl = gamma[slot] * inv;
        sc[slot] = scl;
        sh[slot] = beta[slot] - m * scl;
    }
}

// ---- normalize + ReLU + residual ----
__global__ void final_kernel(const u16* __restrict__ agg, const float* __restrict__ last_x,
                             const float* __restrict__ sc, const float* __restrict__ sh,
                             float* __restrict__ out) {
    int idx = blockIdx.x * blockDim.x + threadIdx.x;   // NN*HD/4 threads
    int c0 = (idx * 4) & 127;
    uint2 a = reinterpret_cast<const uint2*>(agg)[idx];
    float4 lx = reinterpret_cast<const float4*>(last_x)[idx];
    float f0 = __uint_as_float(a.x << 16), f1 = __uint_as_float(a.x & 0xFFFF0000u);
    float f2 = __uint_as_float(a.y << 16), f3 = __uint_as_float(a.y & 0xFFFF0000u);
    float4 o;
    o.x = fmaxf(fmaf(f0, sc[c0 + 0], sh[c0 + 0]), 0.f) + lx.x;
    o.y = fmaxf(fmaf(f1, sc[c0 + 1], sh[c0 + 1]), 0.f) + lx.y;
    o.z = fmaxf(fmaf(f2, sc[c0 + 2], sh[c0 + 2]), 0.f) + lx.z;
    o.w = fmaxf(fmaf(f3, sc[c0 + 3], sh[c0 + 3]), 0.f) + lx.w;
    reinterpret_cast<float4*>(out)[idx] = o;
}

extern "C" void kernel_launch(void* const* d_in, const int* in_sizes, int n_in,
                              void* d_out, int out_size, void* d_ws, size_t ws_size,
                              hipStream_t stream) {
    const float* x      = (const float*)d_in[0];
    const float* last_x = (const float*)d_in[1];
    const int*   edge   = (const int*)d_in[2];   // [2][NE]
    const float* W      = (const float*)d_in[3];
    const float* bias   = (const float*)d_in[4];
    const float* gamma  = (const float*)d_in[5];
    const float* beta   = (const float*)d_in[6];
    float* out = (float*)d_out;

    char* ws = (char*)d_ws;
    size_t p = 0;
    auto take = [&](size_t bytes) { size_t r = p; p += (bytes + 255) & ~255ULL; return r; };
    u32*   bcnt     = (u32*)(ws + take((size_t)(NB + 1) * 4));
    u32*   done     = bcnt + NB;
    u32*   ebuf     = (u32*)(ws + take((size_t)NB * GCAP * 4));
    u32*   rowptr   = (u32*)(ws + take((size_t)(NN + 1) * 4));
    u16*   srclist  = (u16*)(ws + take((size_t)NE * 2));
    float* dinv     = (float*)(ws + take((size_t)NN * 4));
    u16*   xh       = (u16*)(ws + take((size_t)NN * HD * 2));
    u16*   aggX     = (u16*)(ws + take((size_t)NN * HD * 2));
    u16*   aggb     = (u16*)(ws + take((size_t)NN * HD * 2));
    u16*   wf       = (u16*)(ws + take((size_t)HD * HD * 2));
    float* colpart  = (float*)(ws + take((size_t)NBG * 256 * 4));
    float* colpart2 = (float*)(ws + take((size_t)64 * 256 * 4));
    float* sc       = (float*)(ws + take((size_t)HD * 4));
    float* sh       = (float*)(ws + take((size_t)HD * 4));

    const int* srcp = edge;
    const int* dstp = edge + NE;

    hipMemsetAsync(bcnt, 0, (size_t)(NB + 1) * 4, stream);
    prep_part_kernel<<<PART_NBLK + CONV_NBLK, 256, 0, stream>>>(srcp, dstp, x, W, bcnt, ebuf, xh, wf);
    bucket_kernel<<<NB, 256, 0, stream>>>(ebuf, bcnt, rowptr, dinv, srclist);
    agg_kernel<<<(NN + 3) / 4, 256, 0, stream>>>(xh, rowptr, srclist, dinv, aggX);
    gemm_kernel<<<NBG, 256, 0, stream>>>(aggX, wf, bias, aggb, colpart);
    redstat_kernel<<<64, 256, 0, stream>>>(colpart, colpart2, done, gamma, beta, sc, sh);
    final_kernel<<<(NN * HD / 4) / 256, 256, 0, stream>>>(aggb, last_x, sc, sh, out);
}